// Round 1
// baseline (327.199 us; speedup 1.0000x reference)
//
#include <hip/hip_runtime.h>
#include <hip/hip_bf16.h>

// Problem constants
#define N_TOK   16384      // B*T
#define HDIM    2048       // H*d_h
#define NH      16
#define DH      128
#define NPAIRS  120
#define KCHUNKS 4
#define KC_LEN  (N_TOK / KCHUNKS)   // 4096
#define BK      64

// Workspace layout (bytes)
#define SUM_OFF    0u
#define SUMSQ_OFF  8192u
#define MU_OFF     16384u
#define RINV_OFF   24576u
#define WPL_OFF    32768u
#define PC_OFF     36864u                     // 120*128*128 f32 = 7,864,320 B
#define XT_OFF     7901184u                   // 2048*16384 bf16 = 67,108,864 B
// total required ws: ~75 MB

typedef short   bf16x8 __attribute__((ext_vector_type(8)));   // 8 bf16 = 4 VGPRs
typedef float   f32x4  __attribute__((ext_vector_type(4)));

// ---------------------------------------------------------------- pass 1: stats
__global__ void stats_kernel(const float* __restrict__ X,
                             float* __restrict__ sum, float* __restrict__ sumsq) {
    int c4 = blockIdx.x * 256 + threadIdx.x;      // 0..511 float4 columns
    int c  = c4 * 4;
    int n0 = blockIdx.y * 128;                    // 128 rows per block, gridDim.y=128
    float4 s  = make_float4(0.f, 0.f, 0.f, 0.f);
    float4 ss = make_float4(0.f, 0.f, 0.f, 0.f);
    for (int r = 0; r < 128; ++r) {
        float4 x = *(const float4*)(X + (size_t)(n0 + r) * HDIM + c);
        s.x += x.x; s.y += x.y; s.z += x.z; s.w += x.w;
        ss.x += x.x * x.x; ss.y += x.y * x.y; ss.z += x.z * x.z; ss.w += x.w * x.w;
    }
    atomicAdd(&sum[c + 0], s.x);  atomicAdd(&sum[c + 1], s.y);
    atomicAdd(&sum[c + 2], s.z);  atomicAdd(&sum[c + 3], s.w);
    atomicAdd(&sumsq[c + 0], ss.x); atomicAdd(&sumsq[c + 1], ss.y);
    atomicAdd(&sumsq[c + 2], ss.z); atomicAdd(&sumsq[c + 3], ss.w);
}

// ---------------------------------------------------------------- pass 2: mu / rinv
__global__ void finalize_kernel(const float* __restrict__ sum, const float* __restrict__ sumsq,
                                float* __restrict__ mu, float* __restrict__ rinv) {
    int c = blockIdx.x * 256 + threadIdx.x;       // grid 8 x 256 = 2048
    float m = sum[c] * (1.f / (float)N_TOK);
    float var = (sumsq[c] - (float)N_TOK * m * m) * (1.f / (float)(N_TOK - 1));
    var = fmaxf(var, 0.f);
    mu[c]   = m;
    rinv[c] = 1.f / (sqrtf(var) + 1e-8f);
}

// ---------------------------------------------------------------- pass 3: normalize + transpose + bf16
__device__ __forceinline__ unsigned short f2bf(float f) {
    unsigned int u = __float_as_uint(f);
    u += 0x7fffu + ((u >> 16) & 1u);              // round-to-nearest-even
    return (unsigned short)(u >> 16);
}

__global__ void norm_transpose_kernel(const float* __restrict__ X,
                                      const float* __restrict__ mu, const float* __restrict__ rinv,
                                      unsigned short* __restrict__ Xt) {
    __shared__ float tile[64][65];                // +1 pad: conflict-free writes
    int c0 = blockIdx.x * 64;                     // gridDim.x = 32
    int n0 = blockIdx.y * 64;                     // gridDim.y = 256
    int tx = threadIdx.x;
    #pragma unroll
    for (int it = 0; it < 16; ++it) {
        int lin = it * 256 + tx;
        int r = lin >> 6, c = lin & 63;
        float x = X[(size_t)(n0 + r) * HDIM + c0 + c];
        tile[r][c] = (x - mu[c0 + c]) * rinv[c0 + c];
    }
    __syncthreads();
    #pragma unroll
    for (int it = 0; it < 4; ++it) {
        int lin = it * 256 + tx;                  // 1024 items of 4 n-elems
        int g = lin & 15, c = lin >> 4;           // c in 0..63
        ushort4 o;
        o.x = f2bf(tile[g * 4 + 0][c]);
        o.y = f2bf(tile[g * 4 + 1][c]);
        o.z = f2bf(tile[g * 4 + 2][c]);
        o.w = f2bf(tile[g * 4 + 3][c]);
        *(ushort4*)(Xt + (size_t)(c0 + c) * N_TOK + n0 + g * 4) = o;
    }
}

// ---------------------------------------------------------------- pass 4: pairwise Gram via MFMA
__device__ __forceinline__ void gload16(const void* gsrc, void* ldst) {
    __builtin_amdgcn_global_load_lds(
        (const __attribute__((address_space(1))) unsigned int*)gsrc,
        (__attribute__((address_space(3))) unsigned int*)ldst,
        16, 0, 0);
}

__global__ __launch_bounds__(256, 2)
void gram_kernel(const unsigned short* __restrict__ Xt, float* __restrict__ pairC) {
    const int kc = blockIdx.x;                    // K-chunk 0..3
    const int p  = blockIdx.y;                    // pair 0..119
    int i = 0, rem = p;
    while (rem >= NH - 1 - i) { rem -= NH - 1 - i; ++i; }
    const int j = i + 1 + rem;

    __shared__ alignas(16) unsigned short ldsA[128 * BK];   // 16 KB
    __shared__ alignas(16) unsigned short ldsB[128 * BK];   // 16 KB

    const int tx = threadIdx.x;
    const int w  = tx >> 6, l = tx & 63;
    const int wm = w >> 1, wn = w & 1;            // 2x2 wave grid over 128x128
    const int l15 = l & 15, quad = l >> 4;

    // Staging geometry: tile = 128 rows x 8 chunks of 16B. 4 issues x 256 threads.
    // XOR swizzle applied at the SOURCE address (LDS dest is lane-contiguous).
    unsigned int goff[4];                         // byte offset within panel (sans k)
    int ldsOff[4];
    #pragma unroll
    for (int s = 0; s < 4; ++s) {
        int cfl = s * 256 + tx;
        int r = cfl >> 3, cl = cfl & 7;
        int cg = cl ^ (r & 7);
        goff[s]   = (unsigned int)r * (N_TOK * 2) + (unsigned int)cg * 16;
        ldsOff[s] = s * 4096 + w * 1024;          // wave-uniform LDS base per issue
    }
    const char* Abase = (const char*)(Xt + (size_t)i * DH * N_TOK);
    const char* Bbase = (const char*)(Xt + (size_t)j * DH * N_TOK);

    f32x4 acc[4][4];
    #pragma unroll
    for (int mi = 0; mi < 4; ++mi)
        #pragma unroll
        for (int ni = 0; ni < 4; ++ni)
            acc[mi][ni] = (f32x4){0.f, 0.f, 0.f, 0.f};

    int k0 = kc * KC_LEN;
    const int sw = (l15 & 7);                     // row-dependent swizzle term for frag reads
    for (int kt = 0; kt < KC_LEN / BK; ++kt, k0 += BK) {
        size_t kbyte = (size_t)k0 * 2;
        #pragma unroll
        for (int s = 0; s < 4; ++s)
            gload16(Abase + goff[s] + kbyte, (char*)ldsA + ldsOff[s]);
        #pragma unroll
        for (int s = 0; s < 4; ++s)
            gload16(Bbase + goff[s] + kbyte, (char*)ldsB + ldsOff[s]);
        __syncthreads();                          // compiler drains vmcnt before barrier

        #pragma unroll
        for (int kh = 0; kh < 2; ++kh) {          // two K=32 steps per BK=64 tile
            const int q0 = kh * 4 + quad;
            const int c8 = q0 ^ sw;               // swizzled chunk
            bf16x8 a[4], b[4];
            #pragma unroll
            for (int mi = 0; mi < 4; ++mi) {
                int r = wm * 64 + mi * 16 + l15;
                a[mi] = *(const bf16x8*)(ldsA + (r * 8 + c8) * 8);
            }
            #pragma unroll
            for (int ni = 0; ni < 4; ++ni) {
                int r = wn * 64 + ni * 16 + l15;
                b[ni] = *(const bf16x8*)(ldsB + (r * 8 + c8) * 8);
            }
            #pragma unroll
            for (int mi = 0; mi < 4; ++mi)
                #pragma unroll
                for (int ni = 0; ni < 4; ++ni)
                    acc[mi][ni] = __builtin_amdgcn_mfma_f32_16x16x32_bf16(
                        a[mi], b[ni], acc[mi][ni], 0, 0, 0);
        }
        __syncthreads();                          // protect LDS before next staging
    }

    // Epilogue: partial C -> atomic accumulate. C/D: col=lane&15, row=quad*4+reg
    float* pc = pairC + (size_t)p * (DH * DH);
    #pragma unroll
    for (int mi = 0; mi < 4; ++mi)
        #pragma unroll
        for (int ni = 0; ni < 4; ++ni)
            #pragma unroll
            for (int r = 0; r < 4; ++r) {
                int row = wm * 64 + mi * 16 + quad * 4 + r;  // d (head-i dim)
                int col = wn * 64 + ni * 16 + l15;           // e (head-j dim)
                atomicAdd(&pc[row * DH + col], acc[mi][ni][r]);
            }
}

// ---------------------------------------------------------------- pass 5: per-pair loss
__global__ void pair_reduce_kernel(const float* __restrict__ pairC, const float* __restrict__ G,
                                   float* __restrict__ wpl) {
    int p = blockIdx.x;
    int i = 0, rem = p;
    while (rem >= NH - 1 - i) { rem -= NH - 1 - i; ++i; }
    int j = i + 1 + rem;
    const float invN = 1.f / (float)N_TOK;
    const float* pc = pairC + (size_t)p * (DH * DH);
    float s = 0.f;
    for (int idx = threadIdx.x; idx < DH * DH; idx += 256) {
        float v = pc[idx] * invN;
        int d = idx >> 7, e = idx & 127;
        float diff = v - ((d == e) ? 1.f : 0.f);
        s += diff * diff;
    }
    for (int o = 32; o; o >>= 1) s += __shfl_down(s, o);
    __shared__ float red[4];
    if ((threadIdx.x & 63) == 0) red[threadIdx.x >> 6] = s;
    __syncthreads();
    if (threadIdx.x == 0) {
        float t = red[0] + red[1] + red[2] + red[3];
        float x = -15.99f * (G[i * NH + j] - 0.0f);
        float sp = (x > 20.f) ? x : log1pf(expf(x));
        float wgt = 0.929f + (1.f - 0.929f) * sp;
        wpl[p] = wgt * t;
    }
}

__global__ void final_sum_kernel(const float* __restrict__ wpl, float* __restrict__ out) {
    float v = (threadIdx.x < NPAIRS) ? wpl[threadIdx.x] : 0.f;   // 128 threads
    for (int o = 32; o; o >>= 1) v += __shfl_down(v, o);
    __shared__ float r2[2];
    if ((threadIdx.x & 63) == 0) r2[threadIdx.x >> 6] = v;
    __syncthreads();
    if (threadIdx.x == 0) out[0] = (r2[0] + r2[1]) * (1.f / (float)NPAIRS);
}

// ---------------------------------------------------------------- launcher
extern "C" void kernel_launch(void* const* d_in, const int* in_sizes, int n_in,
                              void* d_out, int out_size, void* d_ws, size_t ws_size,
                              hipStream_t stream) {
    const float* X = (const float*)d_in[0];
    const float* G = (const float*)d_in[1];
    float* out = (float*)d_out;
    char* ws = (char*)d_ws;

    float*          sum   = (float*)(ws + SUM_OFF);
    float*          sumsq = (float*)(ws + SUMSQ_OFF);
    float*          mu    = (float*)(ws + MU_OFF);
    float*          rinv  = (float*)(ws + RINV_OFF);
    float*          wpl   = (float*)(ws + WPL_OFF);
    float*          pairC = (float*)(ws + PC_OFF);
    unsigned short* Xt    = (unsigned short*)(ws + XT_OFF);

    hipMemsetAsync(ws + SUM_OFF, 0, 16384, stream);                     // sum+sumsq
    hipMemsetAsync(ws + PC_OFF, 0, (size_t)NPAIRS * DH * DH * 4, stream);

    stats_kernel<<<dim3(2, 128), 256, 0, stream>>>(X, sum, sumsq);
    finalize_kernel<<<8, 256, 0, stream>>>(sum, sumsq, mu, rinv);
    norm_transpose_kernel<<<dim3(32, 256), 256, 0, stream>>>(X, mu, rinv, Xt);
    gram_kernel<<<dim3(KCHUNKS, NPAIRS), 256, 0, stream>>>(Xt, pairC);
    pair_reduce_kernel<<<NPAIRS, 256, 0, stream>>>(pairC, G, wpl);
    final_sum_kernel<<<1, 128, 0, stream>>>(wpl, out);
}